// Round 13
// baseline (248.901 us; speedup 1.0000x reference)
//
#include <hip/hip_runtime.h>

typedef unsigned short ushort_t;
using frag_ab = __attribute__((ext_vector_type(8))) short;
using f32x4   = __attribute__((ext_vector_type(4))) float;
using u32x4   = __attribute__((ext_vector_type(4))) unsigned int;

#define FDIM 512
#define NH 8
#define FATT 64
#define NX 2048
#define NP 4096
#define NTOT 6144

__device__ __forceinline__ ushort_t f2bf(float f) {
    unsigned u = __float_as_uint(f);
    u = (u + 0x7FFFu + ((u >> 16) & 1u)) >> 16;   // RTNE
    return (ushort_t)u;
}
__device__ __forceinline__ float bf2f(ushort_t s) {
    return __uint_as_float(((unsigned)s) << 16);
}
__device__ __forceinline__ unsigned pk2bf(float a, float b) {
    return (unsigned)f2bf(a) | ((unsigned)f2bf(b) << 16);
}

// ---------------------------------------------------------------------------
// K0: fp32 -> bf16 conversions: f = concat(fx, fp0), Wembd, Wfc, Wout
// ---------------------------------------------------------------------------
__global__ __launch_bounds__(256) void k_prep(const float* __restrict__ fx,
                                              const float* __restrict__ fp,
                                              const float* __restrict__ We,
                                              const float* __restrict__ Wfc,
                                              const float* __restrict__ Wout,
                                              ushort_t* __restrict__ f_b,
                                              ushort_t* __restrict__ We_b,
                                              ushort_t* __restrict__ Wfc_b,
                                              ushort_t* __restrict__ Wout_b) {
    int i = blockIdx.x * 256 + threadIdx.x;
    int stride = gridDim.x * 256;
    const int NF4 = NTOT * FDIM / 4;
    const int NX4 = NX * FDIM / 4;
    for (int idx = i; idx < NF4; idx += stride) {
        float4 v = (idx < NX4) ? ((const float4*)fx)[idx]
                               : ((const float4*)fp)[idx - NX4];
        ushort4 o;
        o.x = f2bf(v.x); o.y = f2bf(v.y); o.z = f2bf(v.z); o.w = f2bf(v.w);
        ((ushort4*)f_b)[idx] = o;
    }
    const int NW4 = FDIM * FDIM / 4;
    for (int idx = i; idx < NW4; idx += stride) {
        float4 v = ((const float4*)We)[idx];
        ushort4 o;
        o.x = f2bf(v.x); o.y = f2bf(v.y); o.z = f2bf(v.z); o.w = f2bf(v.w);
        ((ushort4*)We_b)[idx] = o;
    }
    const int NFC4 = NH * FATT * 2 * FATT / 4;
    for (int idx = i; idx < NFC4; idx += stride) {
        float4 v = ((const float4*)Wfc)[idx];
        ushort4 o;
        o.x = f2bf(v.x); o.y = f2bf(v.y); o.z = f2bf(v.z); o.w = f2bf(v.w);
        ((ushort4*)Wfc_b)[idx] = o;
    }
    for (int idx = i; idx < NW4; idx += stride) {
        float4 v = ((const float4*)Wout)[idx];
        ushort4 o;
        o.x = f2bf(v.x); o.y = f2bf(v.y); o.z = f2bf(v.z); o.w = f2bf(v.w);
        ((ushort4*)Wout_b)[idx] = o;
    }
}

// ---------------------------------------------------------------------------
// K1: femb[h][n][e] = f[n] . Wembd[h][e] + bembd  (MFMA GEMM, bf16 out)
//     also writes fpT[h][e][p] (n>=NX) and facat[h][x][64+e] (n<NX)
// ---------------------------------------------------------------------------
__global__ __launch_bounds__(256) void k_embed(const ushort_t* __restrict__ f_b,
                                               const ushort_t* __restrict__ We_b,
                                               const float* __restrict__ bembd,
                                               ushort_t* __restrict__ femb_b,
                                               ushort_t* __restrict__ fpT_b,
                                               ushort_t* __restrict__ facat_b) {
    int tid = threadIdx.x;
    int wv = tid >> 6, lane = tid & 63;
    int g = lane >> 4, c = lane & 15;
    int m0 = blockIdx.x * 64 + wv * 16;
    int o0 = blockIdx.y * 64;

    f32x4 acc[4] = {};
    const ushort_t* arow = f_b + (size_t)(m0 + c) * FDIM + g * 8;
#pragma unroll 4
    for (int ks = 0; ks < FDIM; ks += 32) {
        frag_ab a = *(const frag_ab*)(arow + ks);
#pragma unroll
        for (int t = 0; t < 4; ++t) {
            const ushort_t* brow = We_b + (size_t)(o0 + t * 16 + c) * FDIM + ks + g * 8;
            frag_ab b = *(const frag_ab*)brow;
            acc[t] = __builtin_amdgcn_mfma_f32_16x16x32_bf16(a, b, acc[t], 0, 0, 0);
        }
    }
#pragma unroll
    for (int t = 0; t < 4; ++t) {
        int o = o0 + t * 16 + c;           // output feature = h*64+e
        int h = o >> 6, e = o & 63;
        float bia = bembd[o];
#pragma unroll
        for (int r = 0; r < 4; ++r) {
            int n = m0 + g * 4 + r;
            ushort_t v = f2bf(acc[t][r] + bia);
            femb_b[((size_t)h * NTOT + n) * FATT + e] = v;
            if (n >= NX) fpT_b[((size_t)h * FATT + e) * NP + (n - NX)] = v;
            else         facat_b[((size_t)h * NX + n) * 128 + 64 + e] = v;
        }
    }
}

// ---------------------------------------------------------------------------
// K2: FUSED attention, ILP-restructured. One block per (xt, h), 8 waves,
//   wave owns a 512-p slice. Pass 1: unroll x2 with independent PV
//   accumulator sets (dual dependency chains). Pass 2: unroll x4 with
//   independent store-data registers (4 stores in flight per wave).
// ---------------------------------------------------------------------------
__global__ __launch_bounds__(512) void k_attn_f(const ushort_t* __restrict__ femb_b,
                                                const ushort_t* __restrict__ fpT_b,
                                                float* __restrict__ w_out,
                                                ushort_t* __restrict__ facat_b) {
    int bid = blockIdx.x;
    int h  = bid & 7;                 // XCD affinity
    int xt = bid >> 3;                // 0..127
    int tid = threadIdx.x;
    int wv = tid >> 6;                // 0..7 -> p slice
    int lane = tid & 63;
    int g = lane >> 4, c = lane & 15;

    __shared__ float lds_pv[8][16][64];   // 32 KB: per-wave PV partials
    __shared__ float lds_sum[8][16];      // per-wave row sums
    __shared__ float lds_inv[16];

    const ushort_t* fxb = femb_b + (size_t)h * NTOT * FATT;
    const ushort_t* fpb = fxb + (size_t)NX * FATT;
    const ushort_t* fTb = fpT_b + (size_t)h * FATT * NP;

    // QK B-operand: fx cols (x = xt*16 + c), k = e
    const ushort_t* brow = fxb + (size_t)(xt * 16 + c) * FATT + g * 8;
    frag_ab bx0 = *(const frag_ab*)(brow);
    frag_ab bx1 = *(const frag_ab*)(brow + 32);

    f32x4 pacc[2][4] = {};
    float rsum[2] = {0.f, 0.f};

    // bpermute byte-addrs for PV A-frag relay
    int la4 = (c + ((g & 1) << 5)) << 2;
    int lb4 = la4 + 64;
    int use_hi = g >> 1;

    const int p0 = wv * 512;
    // ---- pass 1: 64 p per outer iteration, two independent chains ----
    for (int ps = p0; ps < p0 + 512; ps += 64) {
#pragma unroll
        for (int u = 0; u < 2; ++u) {
            const int pb = ps + u * 32;
            unsigned tw[2][2];
#pragma unroll
            for (int t = 0; t < 2; ++t) {
                const ushort_t* arow = fpb + (size_t)(pb + t * 16 + c) * FATT + g * 8;
                f32x4 s = {};
                s = __builtin_amdgcn_mfma_f32_16x16x32_bf16(*(const frag_ab*)arow, bx0, s, 0, 0, 0);
                s = __builtin_amdgcn_mfma_f32_16x16x32_bf16(*(const frag_ab*)(arow + 32), bx1, s, 0, 0, 0);
                float e0 = __expf(s[0] * 0.125f);
                float e1 = __expf(s[1] * 0.125f);
                float e2 = __expf(s[2] * 0.125f);
                float e3 = __expf(s[3] * 0.125f);
                rsum[u] += (e0 + e1) + (e2 + e3);
                tw[t][0] = pk2bf(e0, e1);
                tw[t][1] = pk2bf(e2, e3);
            }
            unsigned A0 = __builtin_amdgcn_ds_bpermute(la4, (int)tw[0][0]);
            unsigned A1 = __builtin_amdgcn_ds_bpermute(la4, (int)tw[0][1]);
            unsigned A2 = __builtin_amdgcn_ds_bpermute(lb4, (int)tw[0][0]);
            unsigned A3 = __builtin_amdgcn_ds_bpermute(lb4, (int)tw[0][1]);
            unsigned B0 = __builtin_amdgcn_ds_bpermute(la4, (int)tw[1][0]);
            unsigned B1 = __builtin_amdgcn_ds_bpermute(la4, (int)tw[1][1]);
            unsigned B2 = __builtin_amdgcn_ds_bpermute(lb4, (int)tw[1][0]);
            unsigned B3 = __builtin_amdgcn_ds_bpermute(lb4, (int)tw[1][1]);
            u32x4 paw;
            paw[0] = use_hi ? B0 : A0;
            paw[1] = use_hi ? B1 : A1;
            paw[2] = use_hi ? B2 : A2;
            paw[3] = use_hi ? B3 : A3;
            frag_ab pa = __builtin_bit_cast(frag_ab, paw);
#pragma unroll
            for (int t2 = 0; t2 < 4; ++t2) {
                const ushort_t* vrow = fTb + (size_t)(t2 * 16 + c) * NP + pb + g * 8;
                pacc[u][t2] = __builtin_amdgcn_mfma_f32_16x16x32_bf16(pa, *(const frag_ab*)vrow, pacc[u][t2], 0, 0, 0);
            }
        }
    }

    // merge the two chains
    float rs = rsum[0] + rsum[1];
    rs += __shfl_xor(rs, 16);
    rs += __shfl_xor(rs, 32);
    if (lane < 16) lds_sum[wv][c] = rs;
#pragma unroll
    for (int t2 = 0; t2 < 4; ++t2) {
        f32x4 pt = pacc[0][t2] + pacc[1][t2];
#pragma unroll
        for (int r = 0; r < 4; ++r)
            lds_pv[wv][g * 4 + r][t2 * 16 + c] = pt[r];
    }
    __syncthreads();

    // cross-wave combine: 1024 values over 512 threads (2 each)
#pragma unroll
    for (int k = 0; k < 2; ++k) {
        int v = tid + k * 512;
        int row = v >> 6, e = v & 63;
        float stot = 0.f, val = 0.f;
#pragma unroll
        for (int w = 0; w < 8; ++w) {
            stot += lds_sum[w][row];
            val  += lds_pv[w][row][e];
        }
        facat_b[((size_t)h * NX + xt * 16 + row) * 128 + e] = f2bf(val / stot);
    }
    if (tid < 16) {
        float stot = 0.f;
#pragma unroll
        for (int w = 0; w < 8; ++w) stot += lds_sum[w][tid];
        lds_inv[tid] = 1.f / stot;
    }
    __syncthreads();

    // ---- pass 2: unroll x4 — 4 independent MFMA->exp chains, 4 stores ----
    float inv_c = lds_inv[c];                     // for x = c
    float* wrow = w_out + ((size_t)(xt * 16 + c) * NH + h) * NP;
    for (int ps = p0; ps < p0 + 512; ps += 64) {
        f32x4 o[4];
#pragma unroll
        for (int u = 0; u < 4; ++u) {
            const ushort_t* arow = fpb + (size_t)(ps + u * 16 + c) * FATT + g * 8;
            f32x4 s = {};
            s = __builtin_amdgcn_mfma_f32_16x16x32_bf16(*(const frag_ab*)arow, bx0, s, 0, 0, 0);
            s = __builtin_amdgcn_mfma_f32_16x16x32_bf16(*(const frag_ab*)(arow + 32), bx1, s, 0, 0, 0);
            o[u][0] = __expf(s[0] * 0.125f) * inv_c;
            o[u][1] = __expf(s[1] * 0.125f) * inv_c;
            o[u][2] = __expf(s[2] * 0.125f) * inv_c;
            o[u][3] = __expf(s[3] * 0.125f) * inv_c;
        }
#pragma unroll
        for (int u = 0; u < 4; ++u)
            __builtin_nontemporal_store(o[u], (f32x4*)(wrow + ps + u * 16 + g * 4));
    }
}

// ---------------------------------------------------------------------------
// K3: fc — per-head MFMA GEMM (2048 x 64out x 128k), relu, bf16 out
// ---------------------------------------------------------------------------
__global__ __launch_bounds__(256) void k_fc(const ushort_t* __restrict__ facat_b,
                                            const ushort_t* __restrict__ Wfc_b,
                                            const float* __restrict__ bfc,
                                            ushort_t* __restrict__ fcout_b) {
    int tid = threadIdx.x;
    int wv = tid >> 6, lane = tid & 63;
    int g = lane >> 4, c = lane & 15;
    int x0 = blockIdx.x * 64 + wv * 16;
    int h = blockIdx.y;

    const ushort_t* A = facat_b + ((size_t)h * NX + x0 + c) * 128 + g * 8;
    const ushort_t* B = Wfc_b + (size_t)h * FATT * 128;

    f32x4 acc[4] = {};
#pragma unroll
    for (int ks = 0; ks < 128; ks += 32) {
        frag_ab a = *(const frag_ab*)(A + ks);
#pragma unroll
        for (int t = 0; t < 4; ++t) {
            frag_ab b = *(const frag_ab*)(B + (size_t)(t * 16 + c) * 128 + ks + g * 8);
            acc[t] = __builtin_amdgcn_mfma_f32_16x16x32_bf16(a, b, acc[t], 0, 0, 0);
        }
    }
#pragma unroll
    for (int t = 0; t < 4; ++t) {
        int e = t * 16 + c;
        float bia = bfc[h * FATT + e];
#pragma unroll
        for (int r = 0; r < 4; ++r) {
            int x = x0 + g * 4 + r;
            fcout_b[(size_t)x * FDIM + h * FATT + e] = f2bf(fmaxf(acc[t][r] + bia, 0.f));
        }
    }
}

// ---------------------------------------------------------------------------
// K4: out GEMM (2048 x 512 x 512) MFMA + residual + bias + relu (fp32 out)
// ---------------------------------------------------------------------------
__global__ __launch_bounds__(256) void k_out(const float* __restrict__ fx_in,
                                             const ushort_t* __restrict__ fcout_b,
                                             const ushort_t* __restrict__ Wout_b,
                                             const float* __restrict__ bout,
                                             float* __restrict__ out) {
    int tid = threadIdx.x;
    int wv = tid >> 6, lane = tid & 63;
    int g = lane >> 4, c = lane & 15;
    int x0 = blockIdx.x * 64 + wv * 16;
    int o0 = blockIdx.y * 64;

    f32x4 acc[4] = {};
    const ushort_t* A = fcout_b + (size_t)(x0 + c) * FDIM + g * 8;
#pragma unroll 4
    for (int ks = 0; ks < FDIM; ks += 32) {
        frag_ab a = *(const frag_ab*)(A + ks);
#pragma unroll
        for (int t = 0; t < 4; ++t) {
            frag_ab b = *(const frag_ab*)(Wout_b + (size_t)(o0 + t * 16 + c) * FDIM + ks + g * 8);
            acc[t] = __builtin_amdgcn_mfma_f32_16x16x32_bf16(a, b, acc[t], 0, 0, 0);
        }
    }
#pragma unroll
    for (int t = 0; t < 4; ++t) {
        int f = o0 + t * 16 + c;
        float bia = bout[f];
#pragma unroll
        for (int r = 0; r < 4; ++r) {
            int x = x0 + g * 4 + r;
            float v = acc[t][r] + bia + fx_in[(size_t)x * FDIM + f];
            out[(size_t)x * FDIM + f] = fmaxf(v, 0.f);
        }
    }
}

extern "C" void kernel_launch(void* const* d_in, const int* in_sizes, int n_in,
                              void* d_out, int out_size, void* d_ws, size_t ws_size,
                              hipStream_t stream) {
    const float* fx_in = (const float*)d_in[0];
    const float* fp_in = (const float*)d_in[1];
    const float* Wembd = (const float*)d_in[2];
    const float* bembd = (const float*)d_in[3];
    const float* Wfc   = (const float*)d_in[4];
    const float* bfc   = (const float*)d_in[5];
    const float* Wout  = (const float*)d_in[6];
    const float* bout  = (const float*)d_in[7];

    float* out   = (float*)d_out;
    float* w_out = out + (size_t)NX * FDIM;

    ushort_t* f_b     = (ushort_t*)d_ws;                     // 6144*512
    ushort_t* We_b    = f_b + (size_t)NTOT * FDIM;           // 512*512
    ushort_t* femb_b  = We_b + (size_t)FDIM * FDIM;          // 8*6144*64
    ushort_t* fpT_b   = femb_b + (size_t)NH * NTOT * FATT;   // 8*64*4096
    ushort_t* facat_b = fpT_b + (size_t)NH * FATT * NP;      // 8*2048*128
    ushort_t* fcout_b = facat_b + (size_t)NH * NX * 128;     // 2048*512
    ushort_t* Wfc_b   = fcout_b + (size_t)NX * FDIM;         // 8*64*128
    ushort_t* Wout_b  = Wfc_b + (size_t)NH * FATT * 2 * FATT;// 512*512

    k_prep  <<<1024, 256, 0, stream>>>(fx_in, fp_in, Wembd, Wfc, Wout,
                                       f_b, We_b, Wfc_b, Wout_b);
    k_embed <<<dim3(96, 8), 256, 0, stream>>>(f_b, We_b, bembd, femb_b, fpT_b, facat_b);
    k_attn_f<<<1024, 512, 0, stream>>>(femb_b, fpT_b, w_out, facat_b);
    k_fc    <<<dim3(32, 8), 256, 0, stream>>>(facat_b, Wfc_b, bfc, fcout_b);
    k_out   <<<dim3(32, 8), 256, 0, stream>>>(fx_in, fcout_b, Wout_b, bout, out);
}

// Round 14
// 245.468 us; speedup vs baseline: 1.0140x; 1.0140x over previous
//
#include <hip/hip_runtime.h>

typedef unsigned short ushort_t;
using frag_ab = __attribute__((ext_vector_type(8))) short;
using f32x4   = __attribute__((ext_vector_type(4))) float;
using u32x4   = __attribute__((ext_vector_type(4))) unsigned int;

#define FDIM 512
#define NH 8
#define FATT 64
#define NX 2048
#define NP 4096
#define NTOT 6144

__device__ __forceinline__ ushort_t f2bf(float f) {
    unsigned u = __float_as_uint(f);
    u = (u + 0x7FFFu + ((u >> 16) & 1u)) >> 16;   // RTNE
    return (ushort_t)u;
}
__device__ __forceinline__ float bf2f(ushort_t s) {
    return __uint_as_float(((unsigned)s) << 16);
}
__device__ __forceinline__ unsigned pk2bf(float a, float b) {
    return (unsigned)f2bf(a) | ((unsigned)f2bf(b) << 16);
}

// ---------------------------------------------------------------------------
// K0: fp32 -> bf16 conversions: f = concat(fx, fp0), Wembd, Wfc, Wout
// ---------------------------------------------------------------------------
__global__ __launch_bounds__(256) void k_prep(const float* __restrict__ fx,
                                              const float* __restrict__ fp,
                                              const float* __restrict__ We,
                                              const float* __restrict__ Wfc,
                                              const float* __restrict__ Wout,
                                              ushort_t* __restrict__ f_b,
                                              ushort_t* __restrict__ We_b,
                                              ushort_t* __restrict__ Wfc_b,
                                              ushort_t* __restrict__ Wout_b) {
    int i = blockIdx.x * 256 + threadIdx.x;
    int stride = gridDim.x * 256;
    const int NF4 = NTOT * FDIM / 4;
    const int NX4 = NX * FDIM / 4;
    for (int idx = i; idx < NF4; idx += stride) {
        float4 v = (idx < NX4) ? ((const float4*)fx)[idx]
                               : ((const float4*)fp)[idx - NX4];
        ushort4 o;
        o.x = f2bf(v.x); o.y = f2bf(v.y); o.z = f2bf(v.z); o.w = f2bf(v.w);
        ((ushort4*)f_b)[idx] = o;
    }
    const int NW4 = FDIM * FDIM / 4;
    for (int idx = i; idx < NW4; idx += stride) {
        float4 v = ((const float4*)We)[idx];
        ushort4 o;
        o.x = f2bf(v.x); o.y = f2bf(v.y); o.z = f2bf(v.z); o.w = f2bf(v.w);
        ((ushort4*)We_b)[idx] = o;
    }
    const int NFC4 = NH * FATT * 2 * FATT / 4;
    for (int idx = i; idx < NFC4; idx += stride) {
        float4 v = ((const float4*)Wfc)[idx];
        ushort4 o;
        o.x = f2bf(v.x); o.y = f2bf(v.y); o.z = f2bf(v.z); o.w = f2bf(v.w);
        ((ushort4*)Wfc_b)[idx] = o;
    }
    for (int idx = i; idx < NW4; idx += stride) {
        float4 v = ((const float4*)Wout)[idx];
        ushort4 o;
        o.x = f2bf(v.x); o.y = f2bf(v.y); o.z = f2bf(v.z); o.w = f2bf(v.w);
        ((ushort4*)Wout_b)[idx] = o;
    }
}

// ---------------------------------------------------------------------------
// K1: femb[h][n][e] = f[n] . Wembd[h][e] + bembd  (MFMA GEMM, bf16 out)
//     also writes fpT[h][e][p] (n>=NX) and facat[h][x][64+e] (n<NX)
// ---------------------------------------------------------------------------
__global__ __launch_bounds__(256) void k_embed(const ushort_t* __restrict__ f_b,
                                               const ushort_t* __restrict__ We_b,
                                               const float* __restrict__ bembd,
                                               ushort_t* __restrict__ femb_b,
                                               ushort_t* __restrict__ fpT_b,
                                               ushort_t* __restrict__ facat_b) {
    int tid = threadIdx.x;
    int wv = tid >> 6, lane = tid & 63;
    int g = lane >> 4, c = lane & 15;
    int m0 = blockIdx.x * 64 + wv * 16;
    int o0 = blockIdx.y * 64;

    f32x4 acc[4] = {};
    const ushort_t* arow = f_b + (size_t)(m0 + c) * FDIM + g * 8;
#pragma unroll 4
    for (int ks = 0; ks < FDIM; ks += 32) {
        frag_ab a = *(const frag_ab*)(arow + ks);
#pragma unroll
        for (int t = 0; t < 4; ++t) {
            const ushort_t* brow = We_b + (size_t)(o0 + t * 16 + c) * FDIM + ks + g * 8;
            frag_ab b = *(const frag_ab*)brow;
            acc[t] = __builtin_amdgcn_mfma_f32_16x16x32_bf16(a, b, acc[t], 0, 0, 0);
        }
    }
#pragma unroll
    for (int t = 0; t < 4; ++t) {
        int o = o0 + t * 16 + c;           // output feature = h*64+e
        int h = o >> 6, e = o & 63;
        float bia = bembd[o];
#pragma unroll
        for (int r = 0; r < 4; ++r) {
            int n = m0 + g * 4 + r;
            ushort_t v = f2bf(acc[t][r] + bia);
            femb_b[((size_t)h * NTOT + n) * FATT + e] = v;
            if (n >= NX) fpT_b[((size_t)h * FATT + e) * NP + (n - NX)] = v;
            else         facat_b[((size_t)h * NX + n) * 128 + 64 + e] = v;
        }
    }
}

// ---------------------------------------------------------------------------
// K2: FUSED attention with explicit register software-pipeline (1-deep
//   prefetch via NAMED double-buffered fragments — forces the compiler to
//   keep two load generations in flight instead of serializing on 44 VGPRs).
//   One block per (xt, h), 8 waves, wave owns a 512-p slice.
// ---------------------------------------------------------------------------
__global__ __launch_bounds__(512, 2) void k_attn_f(const ushort_t* __restrict__ femb_b,
                                                   const ushort_t* __restrict__ fpT_b,
                                                   float* __restrict__ w_out,
                                                   ushort_t* __restrict__ facat_b) {
    int bid = blockIdx.x;
    int h  = bid & 7;                 // XCD affinity
    int xt = bid >> 3;                // 0..127
    int tid = threadIdx.x;
    int wv = tid >> 6;                // 0..7 -> p slice
    int lane = tid & 63;
    int g = lane >> 4, c = lane & 15;

    __shared__ float lds_pv[8][16][64];   // 32 KB: per-wave PV partials
    __shared__ float lds_sum[8][16];      // per-wave row sums
    __shared__ float lds_inv[16];

    const ushort_t* fxb = femb_b + (size_t)h * NTOT * FATT;
    const ushort_t* fpb = fxb + (size_t)NX * FATT;
    const ushort_t* fTb = fpT_b + (size_t)h * FATT * NP;

    // QK B-operand: fx cols (x = xt*16 + c), k = e
    const ushort_t* brow = fxb + (size_t)(xt * 16 + c) * FATT + g * 8;
    frag_ab bx0 = *(const frag_ab*)(brow);
    frag_ab bx1 = *(const frag_ab*)(brow + 32);

    f32x4 pacc0 = {}, pacc1 = {}, pacc2 = {}, pacc3 = {};
    float rsum = 0.f;                 // per-lane partial for x = c

    // bpermute byte-addrs for PV A-frag relay
    int la4 = (c + ((g & 1) << 5)) << 2;
    int lb4 = la4 + 64;
    int use_hi = g >> 1;

    const int p0 = wv * 512;

    // ---- pass 1: software-pipelined (prefetch next 8 frags, compute cur) ----
    frag_ab qA0, qA1, qB0, qB1, v0, v1, v2, v3;
    {
        const ushort_t* a0p = fpb + (size_t)(p0 + c) * FATT + g * 8;
        const ushort_t* a1p = fpb + (size_t)(p0 + 16 + c) * FATT + g * 8;
        qA0 = *(const frag_ab*)a0p;  qA1 = *(const frag_ab*)(a0p + 32);
        qB0 = *(const frag_ab*)a1p;  qB1 = *(const frag_ab*)(a1p + 32);
        const ushort_t* vp = fTb + (size_t)c * NP + p0 + g * 8;
        v0 = *(const frag_ab*)(vp);
        v1 = *(const frag_ab*)(vp + (size_t)16 * NP);
        v2 = *(const frag_ab*)(vp + (size_t)32 * NP);
        v3 = *(const frag_ab*)(vp + (size_t)48 * NP);
    }
    for (int ps = p0; ps < p0 + 512; ps += 32) {
        int pn = (ps + 32 < p0 + 512) ? ps + 32 : p0;   // wrap: dummy last prefetch
        // prefetch next iteration's operands into fresh registers
        frag_ab nA0, nA1, nB0, nB1, n0, n1, n2, n3;
        {
            const ushort_t* a0p = fpb + (size_t)(pn + c) * FATT + g * 8;
            const ushort_t* a1p = fpb + (size_t)(pn + 16 + c) * FATT + g * 8;
            nA0 = *(const frag_ab*)a0p;  nA1 = *(const frag_ab*)(a0p + 32);
            nB0 = *(const frag_ab*)a1p;  nB1 = *(const frag_ab*)(a1p + 32);
            const ushort_t* vp = fTb + (size_t)c * NP + pn + g * 8;
            n0 = *(const frag_ab*)(vp);
            n1 = *(const frag_ab*)(vp + (size_t)16 * NP);
            n2 = *(const frag_ab*)(vp + (size_t)32 * NP);
            n3 = *(const frag_ab*)(vp + (size_t)48 * NP);
        }
        // compute with current buffers
        f32x4 sA = {};
        sA = __builtin_amdgcn_mfma_f32_16x16x32_bf16(qA0, bx0, sA, 0, 0, 0);
        sA = __builtin_amdgcn_mfma_f32_16x16x32_bf16(qA1, bx1, sA, 0, 0, 0);
        f32x4 sB = {};
        sB = __builtin_amdgcn_mfma_f32_16x16x32_bf16(qB0, bx0, sB, 0, 0, 0);
        sB = __builtin_amdgcn_mfma_f32_16x16x32_bf16(qB1, bx1, sB, 0, 0, 0);
        float eA0 = __expf(sA[0] * 0.125f);
        float eA1 = __expf(sA[1] * 0.125f);
        float eA2 = __expf(sA[2] * 0.125f);
        float eA3 = __expf(sA[3] * 0.125f);
        float eB0 = __expf(sB[0] * 0.125f);
        float eB1 = __expf(sB[1] * 0.125f);
        float eB2 = __expf(sB[2] * 0.125f);
        float eB3 = __expf(sB[3] * 0.125f);
        rsum += (eA0 + eA1) + (eA2 + eA3) + (eB0 + eB1) + (eB2 + eB3);
        unsigned twA0 = pk2bf(eA0, eA1), twA1 = pk2bf(eA2, eA3);
        unsigned twB0 = pk2bf(eB0, eB1), twB1 = pk2bf(eB2, eB3);
        unsigned A0 = __builtin_amdgcn_ds_bpermute(la4, (int)twA0);
        unsigned A1 = __builtin_amdgcn_ds_bpermute(la4, (int)twA1);
        unsigned A2 = __builtin_amdgcn_ds_bpermute(lb4, (int)twA0);
        unsigned A3 = __builtin_amdgcn_ds_bpermute(lb4, (int)twA1);
        unsigned B0 = __builtin_amdgcn_ds_bpermute(la4, (int)twB0);
        unsigned B1 = __builtin_amdgcn_ds_bpermute(la4, (int)twB1);
        unsigned B2 = __builtin_amdgcn_ds_bpermute(lb4, (int)twB0);
        unsigned B3 = __builtin_amdgcn_ds_bpermute(lb4, (int)twB1);
        u32x4 paw;
        paw[0] = use_hi ? B0 : A0;
        paw[1] = use_hi ? B1 : A1;
        paw[2] = use_hi ? B2 : A2;
        paw[3] = use_hi ? B3 : A3;
        frag_ab pa = __builtin_bit_cast(frag_ab, paw);
        pacc0 = __builtin_amdgcn_mfma_f32_16x16x32_bf16(pa, v0, pacc0, 0, 0, 0);
        pacc1 = __builtin_amdgcn_mfma_f32_16x16x32_bf16(pa, v1, pacc1, 0, 0, 0);
        pacc2 = __builtin_amdgcn_mfma_f32_16x16x32_bf16(pa, v2, pacc2, 0, 0, 0);
        pacc3 = __builtin_amdgcn_mfma_f32_16x16x32_bf16(pa, v3, pacc3, 0, 0, 0);
        // rotate
        qA0 = nA0; qA1 = nA1; qB0 = nB0; qB1 = nB1;
        v0 = n0; v1 = n1; v2 = n2; v3 = n3;
    }

    // in-wave row-sum over g (lane bits 4,5); all lanes end with total for x=c
    rsum += __shfl_xor(rsum, 16);
    rsum += __shfl_xor(rsum, 32);
    if (lane < 16) lds_sum[wv][c] = rsum;
    // PV partials: paccT[r] = PV[x-row g*4+r][e = T*16+c]
#pragma unroll
    for (int r = 0; r < 4; ++r) {
        lds_pv[wv][g * 4 + r][0 * 16 + c] = pacc0[r];
        lds_pv[wv][g * 4 + r][1 * 16 + c] = pacc1[r];
        lds_pv[wv][g * 4 + r][2 * 16 + c] = pacc2[r];
        lds_pv[wv][g * 4 + r][3 * 16 + c] = pacc3[r];
    }
    __syncthreads();

    // cross-wave combine: 1024 values over 512 threads (2 each)
#pragma unroll
    for (int k = 0; k < 2; ++k) {
        int v = tid + k * 512;
        int row = v >> 6, e = v & 63;
        float stot = 0.f, val = 0.f;
#pragma unroll
        for (int w = 0; w < 8; ++w) {
            stot += lds_sum[w][row];
            val  += lds_pv[w][row][e];
        }
        facat_b[((size_t)h * NX + xt * 16 + row) * 128 + e] = f2bf(val / stot);
    }
    if (tid < 16) {
        float stot = 0.f;
#pragma unroll
        for (int w = 0; w < 8; ++w) stot += lds_sum[w][tid];
        lds_inv[tid] = 1.f / stot;
    }
    __syncthreads();

    // ---- pass 2: software-pipelined recompute + NT stores ----
    float inv_c = lds_inv[c];                     // for x = c
    float* wrow = w_out + ((size_t)(xt * 16 + c) * NH + h) * NP;
    frag_ab pA0, pA1, pB0, pB1;
    {
        const ushort_t* a0p = fpb + (size_t)(p0 + c) * FATT + g * 8;
        const ushort_t* a1p = fpb + (size_t)(p0 + 16 + c) * FATT + g * 8;
        pA0 = *(const frag_ab*)a0p;  pA1 = *(const frag_ab*)(a0p + 32);
        pB0 = *(const frag_ab*)a1p;  pB1 = *(const frag_ab*)(a1p + 32);
    }
    for (int ps = p0; ps < p0 + 512; ps += 32) {
        int pn = (ps + 32 < p0 + 512) ? ps + 32 : p0;
        frag_ab nA0, nA1, nB0, nB1;
        {
            const ushort_t* a0p = fpb + (size_t)(pn + c) * FATT + g * 8;
            const ushort_t* a1p = fpb + (size_t)(pn + 16 + c) * FATT + g * 8;
            nA0 = *(const frag_ab*)a0p;  nA1 = *(const frag_ab*)(a0p + 32);
            nB0 = *(const frag_ab*)a1p;  nB1 = *(const frag_ab*)(a1p + 32);
        }
        f32x4 sA = {};
        sA = __builtin_amdgcn_mfma_f32_16x16x32_bf16(pA0, bx0, sA, 0, 0, 0);
        sA = __builtin_amdgcn_mfma_f32_16x16x32_bf16(pA1, bx1, sA, 0, 0, 0);
        f32x4 sB = {};
        sB = __builtin_amdgcn_mfma_f32_16x16x32_bf16(pB0, bx0, sB, 0, 0, 0);
        sB = __builtin_amdgcn_mfma_f32_16x16x32_bf16(pB1, bx1, sB, 0, 0, 0);
        f32x4 oA, oB;
        oA[0] = __expf(sA[0] * 0.125f) * inv_c;
        oA[1] = __expf(sA[1] * 0.125f) * inv_c;
        oA[2] = __expf(sA[2] * 0.125f) * inv_c;
        oA[3] = __expf(sA[3] * 0.125f) * inv_c;
        oB[0] = __expf(sB[0] * 0.125f) * inv_c;
        oB[1] = __expf(sB[1] * 0.125f) * inv_c;
        oB[2] = __expf(sB[2] * 0.125f) * inv_c;
        oB[3] = __expf(sB[3] * 0.125f) * inv_c;
        __builtin_nontemporal_store(oA, (f32x4*)(wrow + ps + g * 4));
        __builtin_nontemporal_store(oB, (f32x4*)(wrow + ps + 16 + g * 4));
        pA0 = nA0; pA1 = nA1; pB0 = nB0; pB1 = nB1;
    }
}

// ---------------------------------------------------------------------------
// K3: fc — per-head MFMA GEMM (2048 x 64out x 128k), relu, bf16 out
// ---------------------------------------------------------------------------
__global__ __launch_bounds__(256) void k_fc(const ushort_t* __restrict__ facat_b,
                                            const ushort_t* __restrict__ Wfc_b,
                                            const float* __restrict__ bfc,
                                            ushort_t* __restrict__ fcout_b) {
    int tid = threadIdx.x;
    int wv = tid >> 6, lane = tid & 63;
    int g = lane >> 4, c = lane & 15;
    int x0 = blockIdx.x * 64 + wv * 16;
    int h = blockIdx.y;

    const ushort_t* A = facat_b + ((size_t)h * NX + x0 + c) * 128 + g * 8;
    const ushort_t* B = Wfc_b + (size_t)h * FATT * 128;

    f32x4 acc[4] = {};
#pragma unroll
    for (int ks = 0; ks < 128; ks += 32) {
        frag_ab a = *(const frag_ab*)(A + ks);
#pragma unroll
        for (int t = 0; t < 4; ++t) {
            frag_ab b = *(const frag_ab*)(B + (size_t)(t * 16 + c) * 128 + ks + g * 8);
            acc[t] = __builtin_amdgcn_mfma_f32_16x16x32_bf16(a, b, acc[t], 0, 0, 0);
        }
    }
#pragma unroll
    for (int t = 0; t < 4; ++t) {
        int e = t * 16 + c;
        float bia = bfc[h * FATT + e];
#pragma unroll
        for (int r = 0; r < 4; ++r) {
            int x = x0 + g * 4 + r;
            fcout_b[(size_t)x * FDIM + h * FATT + e] = f2bf(fmaxf(acc[t][r] + bia, 0.f));
        }
    }
}

// ---------------------------------------------------------------------------
// K4: out GEMM (2048 x 512 x 512) MFMA + residual + bias + relu (fp32 out)
// ---------------------------------------------------------------------------
__global__ __launch_bounds__(256) void k_out(const float* __restrict__ fx_in,
                                             const ushort_t* __restrict__ fcout_b,
                                             const ushort_t* __restrict__ Wout_b,
                                             const float* __restrict__ bout,
                                             float* __restrict__ out) {
    int tid = threadIdx.x;
    int wv = tid >> 6, lane = tid & 63;
    int g = lane >> 4, c = lane & 15;
    int x0 = blockIdx.x * 64 + wv * 16;
    int o0 = blockIdx.y * 64;

    f32x4 acc[4] = {};
    const ushort_t* A = fcout_b + (size_t)(x0 + c) * FDIM + g * 8;
#pragma unroll 4
    for (int ks = 0; ks < FDIM; ks += 32) {
        frag_ab a = *(const frag_ab*)(A + ks);
#pragma unroll
        for (int t = 0; t < 4; ++t) {
            frag_ab b = *(const frag_ab*)(Wout_b + (size_t)(o0 + t * 16 + c) * FDIM + ks + g * 8);
            acc[t] = __builtin_amdgcn_mfma_f32_16x16x32_bf16(a, b, acc[t], 0, 0, 0);
        }
    }
#pragma unroll
    for (int t = 0; t < 4; ++t) {
        int f = o0 + t * 16 + c;
        float bia = bout[f];
#pragma unroll
        for (int r = 0; r < 4; ++r) {
            int x = x0 + g * 4 + r;
            float v = acc[t][r] + bia + fx_in[(size_t)x * FDIM + f];
            out[(size_t)x * FDIM + f] = fmaxf(v, 0.f);
        }
    }
}

extern "C" void kernel_launch(void* const* d_in, const int* in_sizes, int n_in,
                              void* d_out, int out_size, void* d_ws, size_t ws_size,
                              hipStream_t stream) {
    const float* fx_in = (const float*)d_in[0];
    const float* fp_in = (const float*)d_in[1];
    const float* Wembd = (const float*)d_in[2];
    const float* bembd = (const float*)d_in[3];
    const float* Wfc   = (const float*)d_in[4];
    const float* bfc   = (const float*)d_in[5];
    const float* Wout  = (const float*)d_in[6];
    const float* bout  = (const float*)d_in[7];

    float* out   = (float*)d_out;
    float* w_out = out + (size_t)NX * FDIM;

    ushort_t* f_b     = (ushort_t*)d_ws;                     // 6144*512
    ushort_t* We_b    = f_b + (size_t)NTOT * FDIM;           // 512*512
    ushort_t* femb_b  = We_b + (size_t)FDIM * FDIM;          // 8*6144*64
    ushort_t* fpT_b   = femb_b + (size_t)NH * NTOT * FATT;   // 8*64*4096
    ushort_t* facat_b = fpT_b + (size_t)NH * FATT * NP;      // 8*2048*128
    ushort_t* fcout_b = facat_b + (size_t)NH * NX * 128;     // 2048*512
    ushort_t* Wfc_b   = fcout_b + (size_t)NX * FDIM;         // 8*64*128
    ushort_t* Wout_b  = Wfc_b + (size_t)NH * FATT * 2 * FATT;// 512*512

    k_prep  <<<1024, 256, 0, stream>>>(fx_in, fp_in, Wembd, Wfc, Wout,
                                       f_b, We_b, Wfc_b, Wout_b);
    k_embed <<<dim3(96, 8), 256, 0, stream>>>(f_b, We_b, bembd, femb_b, fpT_b, facat_b);
    k_attn_f<<<1024, 512, 0, stream>>>(femb_b, fpT_b, w_out, facat_b);
    k_fc    <<<dim3(32, 8), 256, 0, stream>>>(facat_b, Wfc_b, bfc, fcout_b);
    k_out   <<<dim3(32, 8), 256, 0, stream>>>(fx_in, fcout_b, Wout_b, bout, out);
}